// Round 6
// baseline (136.635 us; speedup 1.0000x reference)
//
#include <hip/hip_runtime.h>
#include <hip/hip_cooperative_groups.h>
#include <stdint.h>

namespace cg = cooperative_groups;

// Problem constants (fixed by reference)
#define N_S 256   // samples
#define K_C 64    // clusters
#define T_L 128   // seq len (contraction dim)
#define F_D 64    // features

typedef short short8 __attribute__((ext_vector_type(8)));
typedef float float4v __attribute__((ext_vector_type(4)));

// ------------------------------------------------------------------
// Single cooperative kernel: 64 blocks x 512 threads (8 waves).
// Phase A : fp32 (row,T,F) -> bf16 (F,row,T) transpose + row sum-of-squares
//           (wave g = blk*8+w owns source row g; 320 rows total).
//           Block 0 also zeroes colsum and loss.
// Phase B : distance (N,K) via bf16 MFMA — identical math/mapping to the
//           verified k_dist (64 blocks = 16 n-tiles x 4 k-tiles).
// Phase C1: q = softmax_k(1/(1+d^2)), 4 rows per block (waves 0-3), store q,
//           block-partial column sums -> atomicAdd into colsum.
// Phase C2: p = softmax_k(q^2/colsum); KL partial per block -> atomicAdd loss.
// ------------------------------------------------------------------
__global__ __launch_bounds__(512) void k_fused(
    const float* __restrict__ x, const float* __restrict__ c,
    uint16_t* __restrict__ xb, uint16_t* __restrict__ cb,
    float* __restrict__ x2, float* __restrict__ c2,
    float* __restrict__ dist, float* __restrict__ colsum,
    float* __restrict__ q, float* __restrict__ loss)
{
    cg::grid_group grid = cg::this_grid();
    const int tid  = threadIdx.x;
    const int lane = tid & 63;
    const int w    = tid >> 6;          // 0..7
    const int blk  = blockIdx.x;        // 0..63

    __shared__ float red[8][16][17];    // phase B cross-wave reduce
    __shared__ float q_s[4][K_C];       // phase C row cache
    __shared__ float part[4][K_C];      // phase C colsum partials
    __shared__ float lpart[4];          // phase C loss partials

    // ---------------- Phase A: convert + squares ----------------
    {
        const int g = blk * 8 + w;      // global wave id, 0..511; rows 0..319
        if (g < 320) {
            const float* src; uint16_t* dst; float* sq;
            if (g < 256) {              // sample rows
                src = x + (size_t)g * T_L * F_D;
                dst = xb + (size_t)lane * N_S * T_L + (size_t)g * T_L;
                sq  = x2 + g * F_D + lane;
            } else {                    // cluster rows
                const int row = g - 256;
                src = c + (size_t)row * T_L * F_D;
                dst = cb + (size_t)lane * K_C * T_L + (size_t)row * T_L;
                sq  = c2 + row * F_D + lane;
            }
            float acc = 0.f;
            for (int t0 = 0; t0 < T_L; t0 += 8) {
                union { uint16_t h[8]; uint4 v; } buf;
                #pragma unroll
                for (int j = 0; j < 8; ++j) {
                    float v = src[(t0 + j) * F_D + lane];
                    acc = fmaf(v, v, acc);
                    uint32_t u = __float_as_uint(v);
                    uint32_t r = (u + 0x7FFFu + ((u >> 16) & 1u)) >> 16;  // RNE
                    buf.h[j] = (uint16_t)r;
                }
                *reinterpret_cast<uint4*>(dst + t0) = buf.v;
            }
            *sq = acc;
        }
        if (blk == 0) {
            if (tid < K_C) colsum[tid] = 0.f;
            if (tid == K_C) loss[0] = 0.f;
        }
    }
    grid.sync();

    // ---------------- Phase B: MFMA distance ----------------
    {
        const int nt  = blk >> 2, kt = blk & 3;
        const int n0  = nt * 16, k0 = kt * 16;
        const int row = lane & 15;      // operand row
        const int tg  = lane >> 4;      // t-subgroup
        const int f0  = w * 8;

        float dsum[4] = {0.f, 0.f, 0.f, 0.f};
        const uint16_t* abase = xb + (size_t)(n0 + row) * T_L + (size_t)tg * 8;
        const uint16_t* bbase = cb + (size_t)(k0 + row) * T_L + (size_t)tg * 8;

        #pragma unroll
        for (int f = 0; f < 8; ++f) {
            const int ff = f0 + f;
            const short8* ap = reinterpret_cast<const short8*>(abase + (size_t)ff * N_S * T_L);
            const short8* bp = reinterpret_cast<const short8*>(bbase + (size_t)ff * K_C * T_L);
            float4v acc = {0.f, 0.f, 0.f, 0.f};
            #pragma unroll
            for (int ts = 0; ts < 4; ++ts)
                acc = __builtin_amdgcn_mfma_f32_16x16x32_bf16(ap[ts * 4], bp[ts * 4], acc, 0, 0, 0);
            // C/D layout: col = lane&15 (cluster), row m = tg*4+reg (sample)
            const float c2v = c2[(k0 + row) * F_D + ff];
            #pragma unroll
            for (int r = 0; r < 4; ++r) {
                const int m = tg * 4 + r;
                const float x2v = x2[(n0 + m) * F_D + ff];
                float d2 = fmaf(-2.0f, acc[r], x2v + c2v);
                dsum[r] += sqrtf(fmaxf(d2, 0.f));
            }
        }
        #pragma unroll
        for (int r = 0; r < 4; ++r) red[w][tg * 4 + r][row] = dsum[r];
        __syncthreads();
        if (tid < 256) {
            const int m = tid >> 4, kl = tid & 15;
            float s = 0.f;
            #pragma unroll
            for (int ww = 0; ww < 8; ++ww) s += red[ww][m][kl];
            dist[(n0 + m) * K_C + (k0 + kl)] = s;
        }
    }
    grid.sync();

    // ---------------- Phase C1: q softmax + colsum partials ----------------
    if (w < 4) {
        const int row = blk * 4 + w;    // 64 blocks x 4 = 256 rows
        const float d = dist[row * K_C + lane];
        const float v = 1.0f / fmaf(d, d, 1.0f);
        float m = v;
        #pragma unroll
        for (int off = 32; off; off >>= 1) m = fmaxf(m, __shfl_xor(m, off));
        const float e = __expf(v - m);
        float s = e;
        #pragma unroll
        for (int off = 32; off; off >>= 1) s += __shfl_xor(s, off);
        const float qv = e / s;
        q[row * K_C + lane] = qv;
        q_s[w][lane]  = qv;
        part[w][lane] = qv;
    }
    __syncthreads();
    if (tid < K_C) {
        const float s = part[0][tid] + part[1][tid] + part[2][tid] + part[3][tid];
        atomicAdd(&colsum[tid], s);
    }
    grid.sync();

    // ---------------- Phase C2: p softmax + KL loss ----------------
    if (w < 4) {
        const float qv = q_s[w][lane];
        const float s  = qv * qv / colsum[lane];
        float m = s;
        #pragma unroll
        for (int off = 32; off; off >>= 1) m = fmaxf(m, __shfl_xor(m, off));
        const float e = __expf(s - m);
        float se = e;
        #pragma unroll
        for (int off = 32; off; off >>= 1) se += __shfl_xor(se, off);
        const float p = e / se;
        float term = qv * (__logf(qv) - p);
        #pragma unroll
        for (int off = 32; off; off >>= 1) term += __shfl_xor(term, off);
        if (lane == 0) lpart[w] = term;
    }
    __syncthreads();
    if (tid == 0) {
        const float t = (lpart[0] + lpart[1] + lpart[2] + lpart[3]) * (1.0f / N_S);
        atomicAdd(loss, t);
    }
}

// ------------------------------------------------------------------
// ws layout (bytes):
//   xb : bf16 (F,N,T)  = 4,194,304
//   cb : bf16 (F,K,T)  = 1,048,576   @ 4194304
//   x2 : f32  (N,F)    =    65,536   @ 5242880
//   c2 : f32  (K,F)    =    16,384   @ 5308416
//   dist: f32 (N,K)    =    65,536   @ 5324800
//   colsum: f32 (K)    =       256   @ 5390336
// total ~5.4 MB
// ------------------------------------------------------------------
extern "C" void kernel_launch(void* const* d_in, const int* in_sizes, int n_in,
                              void* d_out, int out_size, void* d_ws, size_t ws_size,
                              hipStream_t stream)
{
    const float* x = (const float*)d_in[0];
    const float* c = (const float*)d_in[1];
    float* out = (float*)d_out;

    char* ws = (char*)d_ws;
    uint16_t* xb     = (uint16_t*)(ws);
    uint16_t* cb     = (uint16_t*)(ws + 4194304);
    float*    x2     = (float*)(ws + 5242880);
    float*    c2     = (float*)(ws + 5308416);
    float*    dist   = (float*)(ws + 5324800);
    float*    colsum = (float*)(ws + 5390336);

    float* q    = out;          // (N,K) = 16384 f32
    float* loss = out + 16384;  // scalar

    void* args[] = {
        (void*)&x, (void*)&c, (void*)&xb, (void*)&cb, (void*)&x2, (void*)&c2,
        (void*)&dist, (void*)&colsum, (void*)&q, (void*)&loss
    };
    hipLaunchCooperativeKernel((const void*)k_fused, dim3(64), dim3(512),
                               args, 0, stream);
}

// Round 7
// 104.936 us; speedup vs baseline: 1.3021x; 1.3021x over previous
//
#include <hip/hip_runtime.h>
#include <stdint.h>

// Problem constants (fixed by reference)
#define N_S 256   // samples
#define K_C 64    // clusters
#define T_L 128   // seq len (contraction dim)
#define F_D 64    // features

typedef short short8 __attribute__((ext_vector_type(8)));
typedef float float4v __attribute__((ext_vector_type(4)));

// ------------------------------------------------------------------
// Kernel 1: fp32 (row,T,F) -> bf16 (F,row,T) transpose + row sum-of-squares.
// v2: 320 blocks (one row each) x 4 waves (32-t chunk each) = 1280 waves
// (vs 320 before) for better HBM latency hiding. lane = f. Per t-step the
// wave reads 64 consecutive floats (256B coalesced); each lane packs 8
// consecutive-t bf16 into one 16B store. Sum-of-squares via LDS partials.
// ------------------------------------------------------------------
__global__ __launch_bounds__(256) void k_convert(
    const float* __restrict__ x, const float* __restrict__ c,
    uint16_t* __restrict__ xb, uint16_t* __restrict__ cb,
    float* __restrict__ x2, float* __restrict__ c2)
{
    const int tid  = threadIdx.x;
    const int lane = tid & 63;   // feature index
    const int w    = tid >> 6;   // 0..3 : t-chunk
    const int b    = blockIdx.x; // 0..319 : row

    const float* src; uint16_t* dst; float* sqbase;
    if (b < 256) {                      // sample rows
        src    = x  + (size_t)b * T_L * F_D;
        dst    = xb + (size_t)lane * N_S * T_L + (size_t)b * T_L;
        sqbase = x2 + b * F_D;
    } else {                            // cluster rows
        const int row = b - 256;
        src    = c  + (size_t)row * T_L * F_D;
        dst    = cb + (size_t)lane * K_C * T_L + (size_t)row * T_L;
        sqbase = c2 + row * F_D;
    }

    float acc = 0.f;
    const int tlo = w * 32;
    for (int t0 = tlo; t0 < tlo + 32; t0 += 8) {
        union { uint16_t h[8]; uint4 v; } buf;
        #pragma unroll
        for (int j = 0; j < 8; ++j) {
            float v = src[(t0 + j) * F_D + lane];
            acc = fmaf(v, v, acc);
            uint32_t u = __float_as_uint(v);
            uint32_t r = (u + 0x7FFFu + ((u >> 16) & 1u)) >> 16;  // RNE to bf16
            buf.h[j] = (uint16_t)r;
        }
        *reinterpret_cast<uint4*>(dst + t0) = buf.v;
    }

    __shared__ float part[4][F_D];
    part[w][lane] = acc;
    __syncthreads();
    if (tid < F_D)
        sqbase[tid] = part[0][tid] + part[1][tid] + part[2][tid] + part[3][tid];
}

// ------------------------------------------------------------------
// Kernel 2: distance (N,K) via bf16 MFMA.  (verified — byte-identical math)
// Grid: 64 blocks = 16 n-tiles x 4 k-tiles. Block: 512 threads = 8 waves,
// wave w handles f-chunk [8w, 8w+8). Per f: 4 chained mfma_f32_16x16x32_bf16
// over T=128, epilogue d += sqrt(relu(x2 + c2 - 2*xc)), LDS cross-wave reduce.
// ------------------------------------------------------------------
__global__ __launch_bounds__(512) void k_dist(
    const uint16_t* __restrict__ xb, const uint16_t* __restrict__ cb,
    const float* __restrict__ x2, const float* __restrict__ c2,
    float* __restrict__ dist)
{
    const int tid  = threadIdx.x;
    const int lane = tid & 63;
    const int w    = tid >> 6;          // 0..7 : f-chunk
    const int nt   = blockIdx.x >> 2;   // 0..15
    const int kt   = blockIdx.x & 3;    // 0..3
    const int n0   = nt * 16, k0 = kt * 16;
    const int row  = lane & 15;         // operand row (sample for A, cluster for B)
    const int tg   = lane >> 4;         // 0..3 : t-subgroup
    const int f0   = w * 8;

    __shared__ float red[8][16][17];

    float dsum[4] = {0.f, 0.f, 0.f, 0.f};

    const uint16_t* abase = xb + (size_t)(n0 + row) * T_L + (size_t)tg * 8;
    const uint16_t* bbase = cb + (size_t)(k0 + row) * T_L + (size_t)tg * 8;

    #pragma unroll
    for (int f = 0; f < 8; ++f) {
        const int ff = f0 + f;
        const short8* ap = reinterpret_cast<const short8*>(abase + (size_t)ff * N_S * T_L);
        const short8* bp = reinterpret_cast<const short8*>(bbase + (size_t)ff * K_C * T_L);
        float4v acc = {0.f, 0.f, 0.f, 0.f};
        #pragma unroll
        for (int ts = 0; ts < 4; ++ts)
            acc = __builtin_amdgcn_mfma_f32_16x16x32_bf16(ap[ts * 4], bp[ts * 4], acc, 0, 0, 0);
        // C/D layout: col = lane&15 (cluster), row m = tg*4+reg (sample)
        const float c2v = c2[(k0 + row) * F_D + ff];
        #pragma unroll
        for (int r = 0; r < 4; ++r) {
            const int m = tg * 4 + r;
            const float x2v = x2[(n0 + m) * F_D + ff];
            float d2 = fmaf(-2.0f, acc[r], x2v + c2v);
            dsum[r] += sqrtf(fmaxf(d2, 0.f));
        }
    }

    #pragma unroll
    for (int r = 0; r < 4; ++r) red[w][tg * 4 + r][row] = dsum[r];
    __syncthreads();

    if (tid < 256) {
        const int m = tid >> 4, kl = tid & 15;
        float s = 0.f;
        #pragma unroll
        for (int ww = 0; ww < 8; ++ww) s += red[ww][m][kl];
        dist[(n0 + m) * K_C + (k0 + kl)] = s;
    }
}

// ------------------------------------------------------------------
// Kernel 3: tail (verified).  Single block, 1024 threads = 16 waves.
// Phase 1: q = softmax_k(1/(1+d^2)) -> global + LDS.
// Phase 2: column sums in LDS (no atomics, no zero-init).
// Phase 3: p = softmax_k(q^2/colsum), KL term, block reduce, direct store.
// ------------------------------------------------------------------
__global__ __launch_bounds__(1024) void k_tail(
    const float* __restrict__ dist, float* __restrict__ q,
    float* __restrict__ loss)
{
    const int tid  = threadIdx.x;
    const int lane = tid & 63;   // k
    const int w    = tid >> 6;   // 0..15

    __shared__ float q_s[N_S][K_C];     // 64 KB
    __shared__ float part[16][K_C];     // 4 KB
    __shared__ float colsum_s[K_C];
    __shared__ float lpart[16];

    // Phase 1: per-row softmax -> q
    for (int r = 0; r < 16; ++r) {
        const int row = w * 16 + r;
        const float d = dist[row * K_C + lane];
        const float v = 1.0f / fmaf(d, d, 1.0f);
        float m = v;
        #pragma unroll
        for (int off = 32; off; off >>= 1) m = fmaxf(m, __shfl_xor(m, off));
        const float e = __expf(v - m);
        float s = e;
        #pragma unroll
        for (int off = 32; off; off >>= 1) s += __shfl_xor(s, off);
        const float qv = e / s;
        q[row * K_C + lane] = qv;
        q_s[row][lane] = qv;
    }
    __syncthreads();

    // Phase 2: colsum[k] = sum_n q[n][k]
    {
        float acc = 0.f;
        #pragma unroll
        for (int r = 0; r < 16; ++r) acc += q_s[w * 16 + r][lane];
        part[w][lane] = acc;
    }
    __syncthreads();
    if (tid < K_C) {
        float acc = 0.f;
        #pragma unroll
        for (int g = 0; g < 16; ++g) acc += part[g][tid];
        colsum_s[tid] = acc;
    }
    __syncthreads();

    // Phase 3: p-softmax + KL loss
    float tsum = 0.f;
    for (int r = 0; r < 16; ++r) {
        const int row = w * 16 + r;
        const float qv = q_s[row][lane];
        const float s  = qv * qv / colsum_s[lane];
        float m = s;
        #pragma unroll
        for (int off = 32; off; off >>= 1) m = fmaxf(m, __shfl_xor(m, off));
        const float e = __expf(s - m);
        float se = e;
        #pragma unroll
        for (int off = 32; off; off >>= 1) se += __shfl_xor(se, off);
        const float p = e / se;
        tsum += qv * (__logf(qv) - p);
    }
    #pragma unroll
    for (int off = 32; off; off >>= 1) tsum += __shfl_xor(tsum, off);
    if (lane == 0) lpart[w] = tsum;
    __syncthreads();
    if (tid == 0) {
        float t = 0.f;
        #pragma unroll
        for (int g = 0; g < 16; ++g) t += lpart[g];
        loss[0] = t * (1.0f / N_S);
    }
}

// ------------------------------------------------------------------
// ws layout (bytes):
//   xb : bf16 (F,N,T)  = 4,194,304
//   cb : bf16 (F,K,T)  = 1,048,576   @ 4194304
//   x2 : f32  (N,F)    =    65,536   @ 5242880
//   c2 : f32  (K,F)    =    16,384   @ 5308416
//   dist: f32 (N,K)    =    65,536   @ 5324800
// total ~5.4 MB
// ------------------------------------------------------------------
extern "C" void kernel_launch(void* const* d_in, const int* in_sizes, int n_in,
                              void* d_out, int out_size, void* d_ws, size_t ws_size,
                              hipStream_t stream)
{
    const float* x = (const float*)d_in[0];
    const float* c = (const float*)d_in[1];
    float* out = (float*)d_out;

    char* ws = (char*)d_ws;
    uint16_t* xb     = (uint16_t*)(ws);
    uint16_t* cb     = (uint16_t*)(ws + 4194304);
    float*    x2     = (float*)(ws + 5242880);
    float*    c2     = (float*)(ws + 5308416);
    float*    dist   = (float*)(ws + 5324800);

    float* q    = out;          // (N,K) = 16384 f32
    float* loss = out + 16384;  // scalar

    k_convert<<<320, 256, 0, stream>>>(x, c, xb, cb, x2, c2);
    k_dist   <<< 64, 512, 0, stream>>>(xb, cb, x2, c2, dist);
    k_tail   <<<  1, 1024, 0, stream>>>(dist, q, loss);
}